// Round 1
// baseline (840.403 us; speedup 1.0000x reference)
//
#include <hip/hip_runtime.h>

#define DIM 128
#define BN_EPS 1e-5f

// ---------------- degree ----------------
__global__ void k_deg(const int* __restrict__ dst, int* __restrict__ deg, int E) {
    int stride = gridDim.x * blockDim.x;
    for (int e = blockIdx.x * blockDim.x + threadIdx.x; e < E; e += stride)
        atomicAdd(&deg[dst[e]], 1);
}

// ---------------- exclusive scan over N (~50k) in ONE block ----------------
__global__ void k_scan(const int* __restrict__ deg, int* __restrict__ rowptr,
                       float* __restrict__ inv_deg, int n) {
    __shared__ int sums[1024];
    int tid = threadIdx.x;
    int chunk = (n + 1023) >> 10;
    int lo = tid * chunk;
    int hi = lo + chunk;
    if (lo > n) lo = n;
    if (hi > n) hi = n;
    int s = 0;
    for (int i = lo; i < hi; ++i) s += deg[i];
    sums[tid] = s;
    __syncthreads();
    for (int off = 1; off < 1024; off <<= 1) {
        int v = (tid >= off) ? sums[tid - off] : 0;
        __syncthreads();
        if (tid >= off) sums[tid] += v;
        __syncthreads();
    }
    int run = (tid == 0) ? 0 : sums[tid - 1];
    for (int i = lo; i < hi; ++i) {
        rowptr[i] = run;
        int d = deg[i];
        inv_deg[i] = 1.0f / (float)(d > 1 ? d : 1);
        run += d;
    }
    if (tid == 1023) rowptr[n] = run;
}

// ---------------- CSR fill (int atomics for slot assignment) ----------------
__global__ void k_fill(const int* __restrict__ src, const int* __restrict__ dst,
                       const int* __restrict__ rowptr, int* __restrict__ cursor,
                       int* __restrict__ col, int E) {
    int stride = gridDim.x * blockDim.x;
    for (int e = blockIdx.x * blockDim.x + threadIdx.x; e < E; e += stride) {
        int d = dst[e];
        int p = atomicAdd(&cursor[d], 1);
        col[rowptr[d] + p] = src[e];
    }
}

// ---------------- mean aggregation: one wave per node ----------------
__global__ void k_aggregate(const float* __restrict__ x, const int* __restrict__ rowptr,
                            const int* __restrict__ col, const float* __restrict__ inv_deg,
                            float* __restrict__ agg, int n) {
    int gwave = (blockIdx.x * blockDim.x + threadIdx.x) >> 6;
    int lane = threadIdx.x & 63;
    if (gwave >= n) return;
    int lo = rowptr[gwave], hi = rowptr[gwave + 1];
    float ax = 0.f, ay = 0.f;
    for (int j = lo; j < hi; ++j) {
        int s = col[j];
        const float2 v = *(const float2*)(x + (size_t)s * DIM + lane * 2);
        ax += v.x;
        ay += v.y;
    }
    float sc = inv_deg[gwave];
    float2 o;
    o.x = ax * sc;
    o.y = ay * sc;
    *(float2*)(agg + (size_t)gwave * DIM + lane * 2) = o;
}

// ---------------- fused dual-GEMM + bias + BN + ReLU + residual ----------------
// out[r][c] = epilogue( A0[r,:]@W0[:,c] + (A1? A1[r,:]@W1[:,c] : 0) )
// epilogue: h = acc*scl + sh ; h = relu(h) ; h += resid ; store
// tile: 64 rows x 128 cols, 256 threads, thread = 4 rows x 8 cols
__global__ __launch_bounds__(256) void k_gemm(
    const float* __restrict__ A0, const float* __restrict__ W0,
    const float* __restrict__ A1, const float* __restrict__ W1,
    const float* __restrict__ bias,
    const float* __restrict__ gamma, const float* __restrict__ beta,
    const float* __restrict__ mean, const float* __restrict__ var,
    const float* __restrict__ resid,
    float* __restrict__ out, int nrows) {
    __shared__ float Wlds[32][DIM];
    __shared__ float Alds[64][33];   // +1 pad: worst LDS aliasing is 2-way (free)

    const int tid = threadIdx.x;
    const int row0 = blockIdx.x * 64;
    const int tr = tid & 15;   // row group: rows 4*tr .. 4*tr+3
    const int tc = tid >> 4;   // col group: cols 8*tc .. 8*tc+7

    float acc[4][8];
#pragma unroll
    for (int i = 0; i < 4; ++i)
#pragma unroll
        for (int j = 0; j < 8; ++j) acc[i][j] = 0.f;

    for (int seg = 0; seg < 2; ++seg) {
        const float* A = seg ? A1 : A0;
        const float* W = seg ? W1 : W0;
        if (A == nullptr) break;
        for (int kt = 0; kt < 4; ++kt) {
            const int k0 = kt * 32;
            __syncthreads();  // previous compute done before overwriting LDS
            // ---- stage W tile [32][128] (flat-contiguous, fully coalesced) ----
            {
                const float4* Wg = (const float4*)(W + (size_t)k0 * DIM);
                float4* Ws = (float4*)(&Wlds[0][0]);
#pragma unroll
                for (int j = 0; j < 4; ++j) Ws[tid + j * 256] = Wg[tid + j * 256];
            }
            // ---- stage A tile [64 rows][32 k] ----
            {
#pragma unroll
                for (int j = 0; j < 2; ++j) {
                    int f = tid + j * 256;      // float4 index within tile
                    int r = f >> 3;             // tile row
                    int c4 = f & 7;             // float4 within 32 k
                    int grow = row0 + r;
                    float4 v = make_float4(0.f, 0.f, 0.f, 0.f);
                    if (grow < nrows)
                        v = *(const float4*)(A + (size_t)grow * DIM + k0 + c4 * 4);
                    Alds[r][c4 * 4 + 0] = v.x;
                    Alds[r][c4 * 4 + 1] = v.y;
                    Alds[r][c4 * 4 + 2] = v.z;
                    Alds[r][c4 * 4 + 3] = v.w;
                }
            }
            __syncthreads();
            // ---- compute ----
#pragma unroll
            for (int kk = 0; kk < 32; ++kk) {
                float a[4], w[8];
#pragma unroll
                for (int i = 0; i < 4; ++i) a[i] = Alds[4 * tr + i][kk];
#pragma unroll
                for (int j = 0; j < 8; ++j) w[j] = Wlds[kk][8 * tc + j];
#pragma unroll
                for (int i = 0; i < 4; ++i)
#pragma unroll
                    for (int j = 0; j < 8; ++j) acc[i][j] += a[i] * w[j];
            }
        }
    }

    // ---- epilogue: fold bias+BN into per-column scale/shift ----
    float scl[8], sh[8];
#pragma unroll
    for (int j = 0; j < 8; ++j) {
        int c = 8 * tc + j;
        float b = bias ? bias[c] : 0.f;
        if (gamma) {
            float s = gamma[c] * rsqrtf(var[c] + BN_EPS);
            scl[j] = s;
            sh[j] = (b - mean[c]) * s + beta[c];
        } else {
            scl[j] = 1.f;
            sh[j] = b;
        }
    }
#pragma unroll
    for (int i = 0; i < 4; ++i) {
        int r = row0 + 4 * tr + i;
        if (r >= nrows) continue;
        size_t base = (size_t)r * DIM + 8 * tc;
        float vout[8];
#pragma unroll
        for (int j = 0; j < 8; ++j) {
            float h = acc[i][j] * scl[j] + sh[j];
            vout[j] = fmaxf(h, 0.f);
        }
        if (resid) {
            float4 r0 = *(const float4*)(resid + base);
            float4 r1 = *(const float4*)(resid + base + 4);
            vout[0] += r0.x; vout[1] += r0.y; vout[2] += r0.z; vout[3] += r0.w;
            vout[4] += r1.x; vout[5] += r1.y; vout[6] += r1.z; vout[7] += r1.w;
        }
        *(float4*)(out + base) = make_float4(vout[0], vout[1], vout[2], vout[3]);
        *(float4*)(out + base + 4) = make_float4(vout[4], vout[5], vout[6], vout[7]);
    }
}

extern "C" void kernel_launch(void* const* d_in, const int* in_sizes, int n_in,
                              void* d_out, int out_size, void* d_ws, size_t ws_size,
                              hipStream_t stream) {
    const float* x_in = (const float*)d_in[0];
    const int* ei     = (const int*)d_in[1];
    const float* Wp   = (const float*)d_in[2];
    const float* bp   = (const float*)d_in[3];
    const float* Wl   = (const float*)d_in[4];
    const float* bl   = (const float*)d_in[5];
    const float* Wr   = (const float*)d_in[6];
    const float* g    = (const float*)d_in[7];
    const float* be   = (const float*)d_in[8];
    const float* mu   = (const float*)d_in[9];
    const float* va   = (const float*)d_in[10];

    const int N = in_sizes[0] / DIM;
    const int E = in_sizes[1] / 2;
    const int* src = ei;
    const int* dst = ei + E;

    // ---- workspace carve (256B aligned) ----
    char* p = (char*)d_ws;
    auto alloc = [&](size_t bytes) {
        char* r = p;
        p += (bytes + 255) & ~(size_t)255;
        return r;
    };
    float* inv_deg = (float*)alloc((size_t)N * 4);
    int* deg       = (int*)alloc((size_t)N * 4);     // reused as cursor
    int* rowptr    = (int*)alloc((size_t)(N + 1) * 4);
    int* col       = (int*)alloc((size_t)E * 4);
    float* x       = (float*)alloc((size_t)N * DIM * 4);
    float* agg     = (float*)alloc((size_t)N * DIM * 4);

    // ---- CSR build ----
    hipMemsetAsync(deg, 0, (size_t)N * 4, stream);
    k_deg<<<1024, 256, 0, stream>>>(dst, deg, E);
    k_scan<<<1, 1024, 0, stream>>>(deg, rowptr, inv_deg, N);
    hipMemsetAsync(deg, 0, (size_t)N * 4, stream);
    k_fill<<<1024, 256, 0, stream>>>(src, dst, rowptr, deg, col, E);

    const int gblocks = (N + 63) / 64;

    // ---- x = relu(x_in @ Wp + bp) ----
    k_gemm<<<gblocks, 256, 0, stream>>>(x_in, Wp, nullptr, nullptr, bp,
                                        nullptr, nullptr, nullptr, nullptr,
                                        nullptr, x, N);

    float* out = (float*)d_out;
    for (int i = 0; i < 4; ++i) {
        k_aggregate<<<(N + 3) / 4, 256, 0, stream>>>(x, rowptr, col, inv_deg, agg, N);
        const float* Wli = Wl + (size_t)i * DIM * DIM;
        const float* Wri = Wr + (size_t)i * DIM * DIM;
        const float* bli = bl + (size_t)i * DIM;
        // layers 0..2: x = x + relu(bn(h));  layer 3: out = relu(bn(h))
        k_gemm<<<gblocks, 256, 0, stream>>>(agg, Wli, x, Wri, bli,
                                            g + i * DIM, be + i * DIM,
                                            mu + i * DIM, va + i * DIM,
                                            (i < 3) ? x : nullptr,
                                            (i < 3) ? x : out, N);
    }
}

// Round 2
// 625.223 us; speedup vs baseline: 1.3442x; 1.3442x over previous
//
#include <hip/hip_runtime.h>

#define DIM 128
#define BN_EPS 1e-5f

typedef __bf16 bf16x8 __attribute__((ext_vector_type(8)));
typedef float f32x4 __attribute__((ext_vector_type(4)));

__device__ __forceinline__ float bf_e0(unsigned int u) {
    return __builtin_bit_cast(float, u << 16);
}
__device__ __forceinline__ float bf_e1(unsigned int u) {
    return __builtin_bit_cast(float, u & 0xffff0000u);
}
__device__ __forceinline__ unsigned short f2b(float f) {
    __bf16 b = (__bf16)f;  // RTN hardware convert
    return __builtin_bit_cast(unsigned short, b);
}

// ---------------- degree ----------------
__global__ void k_deg(const int* __restrict__ dst, int* __restrict__ deg, int E) {
    int stride = gridDim.x * blockDim.x;
    for (int e = blockIdx.x * blockDim.x + threadIdx.x; e < E; e += stride)
        atomicAdd(&deg[dst[e]], 1);
}

// ---------------- parallel exclusive scan: 3 phases ----------------
#define CHUNK 4
__global__ void k_chunksum(const int* __restrict__ deg, int* __restrict__ csum,
                           int nchunk, int n) {
    int c = blockIdx.x * blockDim.x + threadIdx.x;
    if (c >= nchunk) return;
    int lo = c * CHUNK, hi = min(lo + CHUNK, n);
    int s = 0;
    for (int i = lo; i < hi; ++i) s += deg[i];
    csum[c] = s;
}

__global__ void k_scanchunks(int* __restrict__ csum, int nchunk) {
    __shared__ int sums[1024];
    int tid = threadIdx.x;
    int per = (nchunk + 1023) >> 10;
    int lo = min(tid * per, nchunk);
    int hi = min(lo + per, nchunk);
    int s = 0;
    for (int i = lo; i < hi; ++i) s += csum[i];
    sums[tid] = s;
    __syncthreads();
    for (int off = 1; off < 1024; off <<= 1) {
        int v = (tid >= off) ? sums[tid - off] : 0;
        __syncthreads();
        if (tid >= off) sums[tid] += v;
        __syncthreads();
    }
    int run = (tid == 0) ? 0 : sums[tid - 1];
    for (int i = lo; i < hi; ++i) {
        int t = csum[i];
        csum[i] = run;
        run += t;
    }
}

__global__ void k_scatter(const int* __restrict__ deg, const int* __restrict__ csum,
                          int* __restrict__ rowptr, float* __restrict__ inv_deg,
                          int nchunk, int n, int E) {
    int c = blockIdx.x * blockDim.x + threadIdx.x;
    if (c == 0) rowptr[n] = E;
    if (c >= nchunk) return;
    int run = csum[c];
    int lo = c * CHUNK, hi = min(lo + CHUNK, n);
    for (int i = lo; i < hi; ++i) {
        rowptr[i] = run;
        int d = deg[i];
        inv_deg[i] = 1.0f / (float)(d > 1 ? d : 1);
        run += d;
    }
}

// ---------------- CSR fill ----------------
__global__ void k_fill(const int* __restrict__ src, const int* __restrict__ dst,
                       const int* __restrict__ rowptr, int* __restrict__ cursor,
                       int* __restrict__ col, int E) {
    int stride = gridDim.x * blockDim.x;
    for (int e = blockIdx.x * blockDim.x + threadIdx.x; e < E; e += stride) {
        int d = dst[e];
        int p = atomicAdd(&cursor[d], 1);
        col[rowptr[d] + p] = src[e];
    }
}

// ---------------- fp32 -> bf16 convert ----------------
__global__ void k_cvt(const float* __restrict__ in, unsigned short* __restrict__ out,
                      int n4) {
    int i = blockIdx.x * blockDim.x + threadIdx.x;
    if (i >= n4) return;
    float4 v = *(const float4*)(in + (size_t)i * 4);
    ushort4 o;
    o.x = f2b(v.x); o.y = f2b(v.y); o.z = f2b(v.z); o.w = f2b(v.w);
    *(ushort4*)(out + (size_t)i * 4) = o;
}

// ---------------- weight transpose + bf16: WT[m][n][k] = bf16(W_m[k][n]) ----------------
__global__ void k_wtr(const float* __restrict__ Wp, const float* __restrict__ Wl,
                      const float* __restrict__ Wr, unsigned short* __restrict__ WT) {
    int e = blockIdx.x * blockDim.x + threadIdx.x;
    if (e >= 9 * DIM * DIM) return;
    int m = e / (DIM * DIM);
    int r = e % (DIM * DIM);
    int n = r / DIM;
    int k = r % DIM;
    const float* W = (m == 0) ? Wp : (m < 5) ? (Wl + (size_t)(m - 1) * DIM * DIM)
                                             : (Wr + (size_t)(m - 5) * DIM * DIM);
    WT[e] = f2b(W[(size_t)k * DIM + n]);
}

// ---------------- mean aggregation (bf16 in, bf16 out, fp32 accum) ----------------
__global__ void k_agg(const unsigned int* __restrict__ xb, const int* __restrict__ rowptr,
                      const int* __restrict__ col, const float* __restrict__ inv_deg,
                      unsigned int* __restrict__ aggb, int n) {
    int node = (blockIdx.x * blockDim.x + threadIdx.x) >> 6;
    int lane = threadIdx.x & 63;
    if (node >= n) return;
    int lo = rowptr[node], hi = rowptr[node + 1];
    float ax = 0.f, ay = 0.f;
    for (int j = lo; j < hi; ++j) {
        int s = col[j];
        unsigned int u = xb[(size_t)s * 64 + lane];
        ax += bf_e0(u);
        ay += bf_e1(u);
    }
    float sc = inv_deg[node];
    unsigned int o = (unsigned int)f2b(ax * sc) | ((unsigned int)f2b(ay * sc) << 16);
    aggb[(size_t)node * 64 + lane] = o;
}

// ---------------- MFMA dual-GEMM + bias + BN + ReLU + residual ----------------
// out32[r][c] = epi( A0[r,:]@W0t[c,:]  (+ A1[r,:]@W1t[c,:]) )
// block = 256 thr = 4 waves; wave owns 32 rows (2 MFMA row-tiles) x all 128 cols.
template <int NSEG>
__global__ __launch_bounds__(256) void k_gemm_mfma(
    const unsigned short* __restrict__ A0, const unsigned short* __restrict__ W0,
    const unsigned short* __restrict__ A1, const unsigned short* __restrict__ W1,
    const float* __restrict__ bias,
    const float* __restrict__ gamma, const float* __restrict__ beta,
    const float* __restrict__ mean, const float* __restrict__ var,
    const float* __restrict__ resid,
    float* __restrict__ out32, unsigned short* __restrict__ outb, int nrows) {
    const int lane = threadIdx.x & 63;
    const int wave = threadIdx.x >> 6;
    const int l15 = lane & 15;
    const int lhi = lane >> 4;
    const int row_base = blockIdx.x * 128 + wave * 32;

    f32x4 acc[2][8];
#pragma unroll
    for (int rt = 0; rt < 2; ++rt)
#pragma unroll
        for (int ct = 0; ct < 8; ++ct) acc[rt][ct] = (f32x4){0.f, 0.f, 0.f, 0.f};

    // ---- A fragments: af[rt][s][k] : row = row_base+rt*16+l15, k = k*32+lhi*8..+7
    bf16x8 af[2][NSEG][4];
#pragma unroll
    for (int rt = 0; rt < 2; ++rt) {
        int r = row_base + rt * 16 + l15;
        r = r < nrows ? r : nrows - 1;  // clamp; tail discarded at store
        const unsigned short* a0 = A0 + (size_t)r * DIM + lhi * 8;
#pragma unroll
        for (int k = 0; k < 4; ++k) af[rt][0][k] = *(const bf16x8*)(a0 + k * 32);
        if (NSEG == 2) {
            const unsigned short* a1 = A1 + (size_t)r * DIM + lhi * 8;
#pragma unroll
            for (int k = 0; k < 4; ++k) af[rt][1][k] = *(const bf16x8*)(a1 + k * 32);
        }
    }

    // ---- main: for each (seg, kstep): load 8 B-frags, 16 MFMAs
#pragma unroll
    for (int s = 0; s < NSEG; ++s) {
        const unsigned short* W = s ? W1 : W0;
        const unsigned short* wb = W + (size_t)l15 * DIM + lhi * 8;
#pragma unroll
        for (int k = 0; k < 4; ++k) {
            bf16x8 bf[8];
#pragma unroll
            for (int ct = 0; ct < 8; ++ct)
                bf[ct] = *(const bf16x8*)(wb + (size_t)ct * 16 * DIM + k * 32);
#pragma unroll
            for (int ct = 0; ct < 8; ++ct) {
                acc[0][ct] = __builtin_amdgcn_mfma_f32_16x16x32_bf16(af[0][s][k], bf[ct],
                                                                    acc[0][ct], 0, 0, 0);
                acc[1][ct] = __builtin_amdgcn_mfma_f32_16x16x32_bf16(af[1][s][k], bf[ct],
                                                                    acc[1][ct], 0, 0, 0);
            }
        }
    }

    // ---- epilogue: C/D map col=lane&15, row=(lane>>4)*4+reg ----
#pragma unroll
    for (int ct = 0; ct < 8; ++ct) {
        int c = ct * 16 + l15;
        float scl, sh;
        if (gamma) {
            float s = gamma[c] * rsqrtf(var[c] + BN_EPS);
            scl = s;
            sh = (bias[c] - mean[c]) * s + beta[c];
        } else {
            scl = 1.f;
            sh = bias[c];
        }
#pragma unroll
        for (int rt = 0; rt < 2; ++rt) {
            int rbase = row_base + rt * 16 + lhi * 4;
#pragma unroll
            for (int j = 0; j < 4; ++j) {
                int r = rbase + j;
                if (r >= nrows) continue;
                float h = acc[rt][ct][j] * scl + sh;
                h = fmaxf(h, 0.f);
                size_t off = (size_t)r * DIM + c;
                if (resid) h += resid[off];
                out32[off] = h;
                if (outb) outb[off] = f2b(h);
            }
        }
    }
}

extern "C" void kernel_launch(void* const* d_in, const int* in_sizes, int n_in,
                              void* d_out, int out_size, void* d_ws, size_t ws_size,
                              hipStream_t stream) {
    const float* x_in = (const float*)d_in[0];
    const int* ei     = (const int*)d_in[1];
    const float* Wp   = (const float*)d_in[2];
    const float* bp   = (const float*)d_in[3];
    const float* Wl   = (const float*)d_in[4];
    const float* bl   = (const float*)d_in[5];
    const float* Wr   = (const float*)d_in[6];
    const float* g    = (const float*)d_in[7];
    const float* be   = (const float*)d_in[8];
    const float* mu   = (const float*)d_in[9];
    const float* va   = (const float*)d_in[10];

    const int N = in_sizes[0] / DIM;
    const int E = in_sizes[1] / 2;
    const int* src = ei;
    const int* dst = ei + E;
    const int nchunk = (N + CHUNK - 1) / CHUNK;

    // ---- workspace carve (256B aligned) ----
    char* p = (char*)d_ws;
    auto alloc = [&](size_t bytes) {
        char* r = p;
        p += (bytes + 255) & ~(size_t)255;
        return r;
    };
    float* inv_deg = (float*)alloc((size_t)N * 4);
    int* deg       = (int*)alloc((size_t)N * 4);  // reused as cursor
    int* rowptr    = (int*)alloc((size_t)(N + 1) * 4);
    int* csum      = (int*)alloc((size_t)nchunk * 4);
    int* col       = (int*)alloc((size_t)E * 4);
    float* x32     = (float*)alloc((size_t)N * DIM * 4);
    unsigned short* xb   = (unsigned short*)alloc((size_t)N * DIM * 2);
    unsigned short* aggb = (unsigned short*)alloc((size_t)N * DIM * 2);
    unsigned short* WT   = (unsigned short*)alloc((size_t)9 * DIM * DIM * 2);

    // ---- CSR build ----
    hipMemsetAsync(deg, 0, (size_t)N * 4, stream);
    k_deg<<<1024, 256, 0, stream>>>(dst, deg, E);
    k_chunksum<<<(nchunk + 255) / 256, 256, 0, stream>>>(deg, csum, nchunk, N);
    k_scanchunks<<<1, 1024, 0, stream>>>(csum, nchunk);
    k_scatter<<<(nchunk + 255) / 256, 256, 0, stream>>>(deg, csum, rowptr, inv_deg,
                                                        nchunk, N, E);
    hipMemsetAsync(deg, 0, (size_t)N * 4, stream);
    k_fill<<<1024, 256, 0, stream>>>(src, dst, rowptr, deg, col, E);

    // ---- weights: transpose + bf16 ----
    k_wtr<<<(9 * DIM * DIM + 255) / 256, 256, 0, stream>>>(Wp, Wl, Wr, WT);
    const unsigned short* WpT = WT;
    // ---- x_in -> bf16 ----
    k_cvt<<<(N * DIM / 4 + 255) / 256, 256, 0, stream>>>(x_in, xb, N * DIM / 4);

    const int gblocks = (N + 127) / 128;

    // ---- x = relu(x_in @ Wp + bp):  in-place A0=xb -> writes x32 + xb ----
    k_gemm_mfma<1><<<gblocks, 256, 0, stream>>>(xb, WpT, nullptr, nullptr, bp,
                                                nullptr, nullptr, nullptr, nullptr,
                                                nullptr, x32, xb, N);

    float* out = (float*)d_out;
    for (int i = 0; i < 4; ++i) {
        k_agg<<<(N + 3) / 4, 256, 0, stream>>>((const unsigned int*)xb, rowptr, col,
                                               inv_deg, (unsigned int*)aggb, N);
        const unsigned short* WlT = WT + (size_t)(1 + i) * DIM * DIM;
        const unsigned short* WrT = WT + (size_t)(5 + i) * DIM * DIM;
        k_gemm_mfma<2><<<gblocks, 256, 0, stream>>>(
            aggb, WlT, xb, WrT, bl + i * DIM,
            g + i * DIM, be + i * DIM, mu + i * DIM, va + i * DIM,
            (i < 3) ? x32 : nullptr,
            (i < 3) ? x32 : out, (i < 3) ? xb : nullptr, N);
    }
}

// Round 3
// 458.654 us; speedup vs baseline: 1.8323x; 1.3632x over previous
//
#include <hip/hip_runtime.h>

#define DIM 128
#define BN_EPS 1e-5f

typedef __bf16 bf16x8 __attribute__((ext_vector_type(8)));
typedef float f32x4 __attribute__((ext_vector_type(4)));

__device__ __forceinline__ float bf_e0(unsigned int u) {
    return __builtin_bit_cast(float, u << 16);
}
__device__ __forceinline__ float bf_e1(unsigned int u) {
    return __builtin_bit_cast(float, u & 0xffff0000u);
}
__device__ __forceinline__ unsigned short f2b(float f) {
    __bf16 b = (__bf16)f;  // RTN hardware convert
    return __builtin_bit_cast(unsigned short, b);
}
__device__ __forceinline__ unsigned int pack2(float lo, float hi) {
    return (unsigned int)f2b(lo) | ((unsigned int)f2b(hi) << 16);
}

// ---------------- degree ----------------
__global__ void k_deg(const int* __restrict__ dst, int* __restrict__ deg, int E) {
    int stride = gridDim.x * blockDim.x;
    for (int e = blockIdx.x * blockDim.x + threadIdx.x; e < E; e += stride)
        atomicAdd(&deg[dst[e]], 1);
}

// ---------------- parallel exclusive scan: 3 phases ----------------
#define CHUNK 4
__global__ void k_chunksum(const int* __restrict__ deg, int* __restrict__ csum,
                           int nchunk, int n) {
    int c = blockIdx.x * blockDim.x + threadIdx.x;
    if (c >= nchunk) return;
    int lo = c * CHUNK, hi = min(lo + CHUNK, n);
    int s = 0;
    for (int i = lo; i < hi; ++i) s += deg[i];
    csum[c] = s;
}

__global__ void k_scanchunks(int* __restrict__ csum, int nchunk) {
    __shared__ int sums[1024];
    int tid = threadIdx.x;
    int per = (nchunk + 1023) >> 10;
    int lo = min(tid * per, nchunk);
    int hi = min(lo + per, nchunk);
    int s = 0;
    for (int i = lo; i < hi; ++i) s += csum[i];
    sums[tid] = s;
    __syncthreads();
    for (int off = 1; off < 1024; off <<= 1) {
        int v = (tid >= off) ? sums[tid - off] : 0;
        __syncthreads();
        if (tid >= off) sums[tid] += v;
        __syncthreads();
    }
    int run = (tid == 0) ? 0 : sums[tid - 1];
    for (int i = lo; i < hi; ++i) {
        int t = csum[i];
        csum[i] = run;
        run += t;
    }
}

__global__ void k_scatter(const int* __restrict__ deg, const int* __restrict__ csum,
                          int* __restrict__ rowptr, float* __restrict__ inv_deg,
                          int nchunk, int n, int E) {
    int c = blockIdx.x * blockDim.x + threadIdx.x;
    if (c == 0) rowptr[n] = E;
    if (c >= nchunk) return;
    int run = csum[c];
    int lo = c * CHUNK, hi = min(lo + CHUNK, n);
    for (int i = lo; i < hi; ++i) {
        rowptr[i] = run;
        int d = deg[i];
        inv_deg[i] = 1.0f / (float)(d > 1 ? d : 1);
        run += d;
    }
}

// ---------------- CSR fill ----------------
__global__ void k_fill(const int* __restrict__ src, const int* __restrict__ dst,
                       const int* __restrict__ rowptr, int* __restrict__ cursor,
                       int* __restrict__ col, int E) {
    int stride = gridDim.x * blockDim.x;
    for (int e = blockIdx.x * blockDim.x + threadIdx.x; e < E; e += stride) {
        int d = dst[e];
        int p = atomicAdd(&cursor[d], 1);
        col[rowptr[d] + p] = src[e];
    }
}

// ---------------- fp32 -> bf16 convert ----------------
__global__ void k_cvt(const float* __restrict__ in, unsigned short* __restrict__ out,
                      int n4) {
    int i = blockIdx.x * blockDim.x + threadIdx.x;
    if (i >= n4) return;
    float4 v = *(const float4*)(in + (size_t)i * 4);
    ushort4 o;
    o.x = f2b(v.x); o.y = f2b(v.y); o.z = f2b(v.z); o.w = f2b(v.w);
    *(ushort4*)(out + (size_t)i * 4) = o;
}

// ---------------- weight transpose + bf16: WT[m][n][k] = bf16(W_m[k][n]) ----------------
__global__ void k_wtr(const float* __restrict__ Wp, const float* __restrict__ Wl,
                      const float* __restrict__ Wr, unsigned short* __restrict__ WT) {
    int e = blockIdx.x * blockDim.x + threadIdx.x;
    if (e >= 9 * DIM * DIM) return;
    int m = e / (DIM * DIM);
    int r = e % (DIM * DIM);
    int n = r / DIM;
    int k = r % DIM;
    const float* W = (m == 0) ? Wp : (m < 5) ? (Wl + (size_t)(m - 1) * DIM * DIM)
                                             : (Wr + (size_t)(m - 5) * DIM * DIM);
    WT[e] = f2b(W[(size_t)k * DIM + n]);
}

// ---------------- mean aggregation: wave = 1 node, 4 edge-groups x 16 lanes ----
// lane (e4,c16): gathers uint4 (8 bf16) of row col[j+e4] at column c16*8.
// End: shfl_xor reduce over edge-groups, lanes 0-15 store the 256B row.
__global__ void k_agg(const uint4* __restrict__ xb4, const int* __restrict__ rowptr,
                      const int* __restrict__ col, const float* __restrict__ inv_deg,
                      uint4* __restrict__ aggb4, int n) {
    int node = (blockIdx.x * blockDim.x + threadIdx.x) >> 6;
    int lane = threadIdx.x & 63;
    if (node >= n) return;
    const int e4 = lane >> 4, c16 = lane & 15;
    const int lo = rowptr[node], hi = rowptr[node + 1];

    float a0 = 0.f, a1 = 0.f, a2 = 0.f, a3 = 0.f,
          a4 = 0.f, a5 = 0.f, a6 = 0.f, a7 = 0.f;

    int idx = lo + e4;
    int s_pre = (idx < hi) ? col[idx] : -1;  // prefetched col for this iter
    for (int j = lo; j < hi; j += 4) {
        int s = s_pre;
        int nidx = j + 4 + e4;
        s_pre = (nidx < hi) ? col[nidx] : -1;  // overlap next col load with gather
        if (s >= 0) {
            uint4 v = xb4[(size_t)s * 16 + c16];
            a0 += bf_e0(v.x); a1 += bf_e1(v.x);
            a2 += bf_e0(v.y); a3 += bf_e1(v.y);
            a4 += bf_e0(v.z); a5 += bf_e1(v.z);
            a6 += bf_e0(v.w); a7 += bf_e1(v.w);
        }
    }
#define RED_(a) a += __shfl_xor(a, 16); a += __shfl_xor(a, 32);
    RED_(a0) RED_(a1) RED_(a2) RED_(a3) RED_(a4) RED_(a5) RED_(a6) RED_(a7)
#undef RED_
    float sc = inv_deg[node];
    uint4 o;
    o.x = pack2(a0 * sc, a1 * sc);
    o.y = pack2(a2 * sc, a3 * sc);
    o.z = pack2(a4 * sc, a5 * sc);
    o.w = pack2(a6 * sc, a7 * sc);
    if (lane < 16) aggb4[(size_t)node * 16 + c16] = o;
}

// ---------------- MFMA dual-GEMM + bias + BN + ReLU + residual ----------------
template <int NSEG>
__global__ __launch_bounds__(256) void k_gemm_mfma(
    const unsigned short* __restrict__ A0, const unsigned short* __restrict__ W0,
    const unsigned short* __restrict__ A1, const unsigned short* __restrict__ W1,
    const float* __restrict__ bias,
    const float* __restrict__ gamma, const float* __restrict__ beta,
    const float* __restrict__ mean, const float* __restrict__ var,
    const float* __restrict__ resid,
    float* __restrict__ out32, unsigned short* __restrict__ outb, int nrows) {
    const int lane = threadIdx.x & 63;
    const int wave = threadIdx.x >> 6;
    const int l15 = lane & 15;
    const int lhi = lane >> 4;
    const int row_base = blockIdx.x * 128 + wave * 32;

    f32x4 acc[2][8];
#pragma unroll
    for (int rt = 0; rt < 2; ++rt)
#pragma unroll
        for (int ct = 0; ct < 8; ++ct) acc[rt][ct] = (f32x4){0.f, 0.f, 0.f, 0.f};

    bf16x8 af[2][NSEG][4];
#pragma unroll
    for (int rt = 0; rt < 2; ++rt) {
        int r = row_base + rt * 16 + l15;
        r = r < nrows ? r : nrows - 1;  // clamp; tail discarded at store
        const unsigned short* a0 = A0 + (size_t)r * DIM + lhi * 8;
#pragma unroll
        for (int k = 0; k < 4; ++k) af[rt][0][k] = *(const bf16x8*)(a0 + k * 32);
        if (NSEG == 2) {
            const unsigned short* a1 = A1 + (size_t)r * DIM + lhi * 8;
#pragma unroll
            for (int k = 0; k < 4; ++k) af[rt][1][k] = *(const bf16x8*)(a1 + k * 32);
        }
    }

#pragma unroll
    for (int s = 0; s < NSEG; ++s) {
        const unsigned short* W = s ? W1 : W0;
        const unsigned short* wb = W + (size_t)l15 * DIM + lhi * 8;
#pragma unroll
        for (int k = 0; k < 4; ++k) {
            bf16x8 bf[8];
#pragma unroll
            for (int ct = 0; ct < 8; ++ct)
                bf[ct] = *(const bf16x8*)(wb + (size_t)ct * 16 * DIM + k * 32);
#pragma unroll
            for (int ct = 0; ct < 8; ++ct) {
                acc[0][ct] = __builtin_amdgcn_mfma_f32_16x16x32_bf16(af[0][s][k], bf[ct],
                                                                    acc[0][ct], 0, 0, 0);
                acc[1][ct] = __builtin_amdgcn_mfma_f32_16x16x32_bf16(af[1][s][k], bf[ct],
                                                                    acc[1][ct], 0, 0, 0);
            }
        }
    }

    // ---- epilogue: C/D map col=lane&15, row=(lane>>4)*4+reg ----
#pragma unroll
    for (int ct = 0; ct < 8; ++ct) {
        int c = ct * 16 + l15;
        float scl, sh;
        if (gamma) {
            float s = gamma[c] * rsqrtf(var[c] + BN_EPS);
            scl = s;
            sh = (bias[c] - mean[c]) * s + beta[c];
        } else {
            scl = 1.f;
            sh = bias[c];
        }
#pragma unroll
        for (int rt = 0; rt < 2; ++rt) {
            int rbase = row_base + rt * 16 + lhi * 4;
#pragma unroll
            for (int j = 0; j < 4; ++j) {
                int r = rbase + j;
                if (r >= nrows) continue;
                float h = acc[rt][ct][j] * scl + sh;
                h = fmaxf(h, 0.f);
                size_t off = (size_t)r * DIM + c;
                if (resid) h += resid[off];
                out32[off] = h;
                if (outb) outb[off] = f2b(h);
            }
        }
    }
}

extern "C" void kernel_launch(void* const* d_in, const int* in_sizes, int n_in,
                              void* d_out, int out_size, void* d_ws, size_t ws_size,
                              hipStream_t stream) {
    const float* x_in = (const float*)d_in[0];
    const int* ei     = (const int*)d_in[1];
    const float* Wp   = (const float*)d_in[2];
    const float* bp   = (const float*)d_in[3];
    const float* Wl   = (const float*)d_in[4];
    const float* bl   = (const float*)d_in[5];
    const float* Wr   = (const float*)d_in[6];
    const float* g    = (const float*)d_in[7];
    const float* be   = (const float*)d_in[8];
    const float* mu   = (const float*)d_in[9];
    const float* va   = (const float*)d_in[10];

    const int N = in_sizes[0] / DIM;
    const int E = in_sizes[1] / 2;
    const int* src = ei;
    const int* dst = ei + E;
    const int nchunk = (N + CHUNK - 1) / CHUNK;

    // ---- workspace carve (256B aligned) ----
    char* p = (char*)d_ws;
    auto alloc = [&](size_t bytes) {
        char* r = p;
        p += (bytes + 255) & ~(size_t)255;
        return r;
    };
    float* inv_deg = (float*)alloc((size_t)N * 4);
    int* deg       = (int*)alloc((size_t)N * 4);  // reused as cursor
    int* rowptr    = (int*)alloc((size_t)(N + 1) * 4);
    int* csum      = (int*)alloc((size_t)nchunk * 4);
    int* col       = (int*)alloc((size_t)E * 4);
    float* x32     = (float*)alloc((size_t)N * DIM * 4);
    unsigned short* xb   = (unsigned short*)alloc((size_t)N * DIM * 2);
    unsigned short* aggb = (unsigned short*)alloc((size_t)N * DIM * 2);
    unsigned short* WT   = (unsigned short*)alloc((size_t)9 * DIM * DIM * 2);

    // ---- CSR build ----
    hipMemsetAsync(deg, 0, (size_t)N * 4, stream);
    k_deg<<<1024, 256, 0, stream>>>(dst, deg, E);
    k_chunksum<<<(nchunk + 255) / 256, 256, 0, stream>>>(deg, csum, nchunk, N);
    k_scanchunks<<<1, 1024, 0, stream>>>(csum, nchunk);
    k_scatter<<<(nchunk + 255) / 256, 256, 0, stream>>>(deg, csum, rowptr, inv_deg,
                                                        nchunk, N, E);
    hipMemsetAsync(deg, 0, (size_t)N * 4, stream);
    k_fill<<<1024, 256, 0, stream>>>(src, dst, rowptr, deg, col, E);

    // ---- weights: transpose + bf16 ----
    k_wtr<<<(9 * DIM * DIM + 255) / 256, 256, 0, stream>>>(Wp, Wl, Wr, WT);
    const unsigned short* WpT = WT;
    // ---- x_in -> bf16 ----
    k_cvt<<<(N * DIM / 4 + 255) / 256, 256, 0, stream>>>(x_in, xb, N * DIM / 4);

    const int gblocks = (N + 127) / 128;

    // ---- x = relu(x_in @ Wp + bp) ----
    k_gemm_mfma<1><<<gblocks, 256, 0, stream>>>(xb, WpT, nullptr, nullptr, bp,
                                                nullptr, nullptr, nullptr, nullptr,
                                                nullptr, x32, xb, N);

    float* out = (float*)d_out;
    for (int i = 0; i < 4; ++i) {
        k_agg<<<(N + 3) / 4, 256, 0, stream>>>((const uint4*)xb, rowptr, col,
                                               inv_deg, (uint4*)aggb, N);
        const unsigned short* WlT = WT + (size_t)(1 + i) * DIM * DIM;
        const unsigned short* WrT = WT + (size_t)(5 + i) * DIM * DIM;
        k_gemm_mfma<2><<<gblocks, 256, 0, stream>>>(
            aggb, WlT, xb, WrT, bl + i * DIM,
            g + i * DIM, be + i * DIM, mu + i * DIM, va + i * DIM,
            (i < 3) ? x32 : nullptr,
            (i < 3) ? x32 : out, (i < 3) ? xb : nullptr, N);
    }
}

// Round 4
// 458.196 us; speedup vs baseline: 1.8342x; 1.0010x over previous
//
#include <hip/hip_runtime.h>

#define DIM 128
#define BN_EPS 1e-5f

typedef __bf16 bf16x8 __attribute__((ext_vector_type(8)));
typedef float f32x4 __attribute__((ext_vector_type(4)));

__device__ __forceinline__ float bf_e0(unsigned int u) {
    return __builtin_bit_cast(float, u << 16);
}
__device__ __forceinline__ float bf_e1(unsigned int u) {
    return __builtin_bit_cast(float, u & 0xffff0000u);
}
__device__ __forceinline__ float b2f(unsigned short s) {
    return __builtin_bit_cast(float, (unsigned int)s << 16);
}
__device__ __forceinline__ unsigned short f2b(float f) {
    __bf16 b = (__bf16)f;  // RTN hardware convert
    return __builtin_bit_cast(unsigned short, b);
}
__device__ __forceinline__ unsigned int pack2(float lo, float hi) {
    return (unsigned int)f2b(lo) | ((unsigned int)f2b(hi) << 16);
}

// ---------------- degree ----------------
__global__ void k_deg(const int* __restrict__ dst, int* __restrict__ deg, int E) {
    int stride = gridDim.x * blockDim.x;
    for (int e = blockIdx.x * blockDim.x + threadIdx.x; e < E; e += stride)
        atomicAdd(&deg[dst[e]], 1);
}

// ---------------- parallel exclusive scan: 3 phases ----------------
#define CHUNK 4
__global__ void k_chunksum(const int* __restrict__ deg, int* __restrict__ csum,
                           int nchunk, int n) {
    int c = blockIdx.x * blockDim.x + threadIdx.x;
    if (c >= nchunk) return;
    int lo = c * CHUNK, hi = min(lo + CHUNK, n);
    int s = 0;
    for (int i = lo; i < hi; ++i) s += deg[i];
    csum[c] = s;
}

__global__ void k_scanchunks(int* __restrict__ csum, int nchunk) {
    __shared__ int sums[1024];
    int tid = threadIdx.x;
    int per = (nchunk + 1023) >> 10;
    int lo = min(tid * per, nchunk);
    int hi = min(lo + per, nchunk);
    int s = 0;
    for (int i = lo; i < hi; ++i) s += csum[i];
    sums[tid] = s;
    __syncthreads();
    for (int off = 1; off < 1024; off <<= 1) {
        int v = (tid >= off) ? sums[tid - off] : 0;
        __syncthreads();
        if (tid >= off) sums[tid] += v;
        __syncthreads();
    }
    int run = (tid == 0) ? 0 : sums[tid - 1];
    for (int i = lo; i < hi; ++i) {
        int t = csum[i];
        csum[i] = run;
        run += t;
    }
}

__global__ void k_scatter(const int* __restrict__ deg, const int* __restrict__ csum,
                          int* __restrict__ rowptr, float* __restrict__ inv_deg,
                          int nchunk, int n, int E) {
    int c = blockIdx.x * blockDim.x + threadIdx.x;
    if (c == 0) rowptr[n] = E;
    if (c >= nchunk) return;
    int run = csum[c];
    int lo = c * CHUNK, hi = min(lo + CHUNK, n);
    for (int i = lo; i < hi; ++i) {
        rowptr[i] = run;
        int d = deg[i];
        inv_deg[i] = 1.0f / (float)(d > 1 ? d : 1);
        run += d;
    }
}

// ---------------- CSR fill ----------------
__global__ void k_fill(const int* __restrict__ src, const int* __restrict__ dst,
                       const int* __restrict__ rowptr, int* __restrict__ cursor,
                       int* __restrict__ col, int E) {
    int stride = gridDim.x * blockDim.x;
    for (int e = blockIdx.x * blockDim.x + threadIdx.x; e < E; e += stride) {
        int d = dst[e];
        int p = atomicAdd(&cursor[d], 1);
        col[rowptr[d] + p] = src[e];
    }
}

// ---------------- fp32 -> bf16 convert ----------------
__global__ void k_cvt(const float* __restrict__ in, unsigned short* __restrict__ out,
                      int n4) {
    int i = blockIdx.x * blockDim.x + threadIdx.x;
    if (i >= n4) return;
    float4 v = *(const float4*)(in + (size_t)i * 4);
    ushort4 o;
    o.x = f2b(v.x); o.y = f2b(v.y); o.z = f2b(v.z); o.w = f2b(v.w);
    *(ushort4*)(out + (size_t)i * 4) = o;
}

// ---------------- weight transpose + bf16: WT[m][n][k] = bf16(W_m[k][n]) ----------------
__global__ void k_wtr(const float* __restrict__ Wp, const float* __restrict__ Wl,
                      const float* __restrict__ Wr, unsigned short* __restrict__ WT) {
    int e = blockIdx.x * blockDim.x + threadIdx.x;
    if (e >= 9 * DIM * DIM) return;
    int m = e / (DIM * DIM);
    int r = e % (DIM * DIM);
    int n = r / DIM;
    int k = r % DIM;
    const float* W = (m == 0) ? Wp : (m < 5) ? (Wl + (size_t)(m - 1) * DIM * DIM)
                                             : (Wr + (size_t)(m - 5) * DIM * DIM);
    WT[e] = f2b(W[(size_t)k * DIM + n]);
}

// ---------------- mean aggregation: wave = 1 node, 4 edge-groups x 16 lanes ----
__global__ void k_agg(const uint4* __restrict__ xb4, const int* __restrict__ rowptr,
                      const int* __restrict__ col, const float* __restrict__ inv_deg,
                      uint4* __restrict__ aggb4, int n) {
    int node = (blockIdx.x * blockDim.x + threadIdx.x) >> 6;
    int lane = threadIdx.x & 63;
    if (node >= n) return;
    const int e4 = lane >> 4, c16 = lane & 15;
    const int lo = rowptr[node], hi = rowptr[node + 1];

    float a0 = 0.f, a1 = 0.f, a2 = 0.f, a3 = 0.f,
          a4 = 0.f, a5 = 0.f, a6 = 0.f, a7 = 0.f;

    int idx = lo + e4;
    int s_pre = (idx < hi) ? col[idx] : -1;  // prefetched col for this iter
    for (int j = lo; j < hi; j += 4) {
        int s = s_pre;
        int nidx = j + 4 + e4;
        s_pre = (nidx < hi) ? col[nidx] : -1;  // overlap next col load with gather
        if (s >= 0) {
            uint4 v = xb4[(size_t)s * 16 + c16];
            a0 += bf_e0(v.x); a1 += bf_e1(v.x);
            a2 += bf_e0(v.y); a3 += bf_e1(v.y);
            a4 += bf_e0(v.z); a5 += bf_e1(v.z);
            a6 += bf_e0(v.w); a7 += bf_e1(v.w);
        }
    }
#define RED_(a) a += __shfl_xor(a, 16); a += __shfl_xor(a, 32);
    RED_(a0) RED_(a1) RED_(a2) RED_(a3) RED_(a4) RED_(a5) RED_(a6) RED_(a7)
#undef RED_
    float sc = inv_deg[node];
    uint4 o;
    o.x = pack2(a0 * sc, a1 * sc);
    o.y = pack2(a2 * sc, a3 * sc);
    o.z = pack2(a4 * sc, a5 * sc);
    o.w = pack2(a6 * sc, a7 * sc);
    if (lane < 16) aggb4[(size_t)node * 16 + c16] = o;
}

// ---------------- MFMA dual-GEMM + bias + BN + ReLU + bf16 residual ----------------
// wave = 16 rows x 128 cols; block = 4 waves = 64 rows; grid = N/64.
// residb: bf16 residual (read); out32 (fp32) and/or outb (bf16) written.
template <int NSEG>
__global__ __launch_bounds__(256) void k_gemm_mfma(
    const unsigned short* __restrict__ A0, const unsigned short* __restrict__ W0,
    const unsigned short* __restrict__ A1, const unsigned short* __restrict__ W1,
    const float* __restrict__ bias,
    const float* __restrict__ gamma, const float* __restrict__ beta,
    const float* __restrict__ mean, const float* __restrict__ var,
    const unsigned short* __restrict__ residb,
    float* __restrict__ out32, unsigned short* __restrict__ outb, int nrows) {
    const int lane = threadIdx.x & 63;
    const int wave = threadIdx.x >> 6;
    const int l15 = lane & 15;
    const int lhi = lane >> 4;
    const int row_base = blockIdx.x * 64 + wave * 16;

    f32x4 acc[8];
#pragma unroll
    for (int ct = 0; ct < 8; ++ct) acc[ct] = (f32x4){0.f, 0.f, 0.f, 0.f};

    // ---- A fragments: row = row_base + l15, k = k*32 + lhi*8 .. +7
    bf16x8 af[NSEG][4];
    {
        int r = row_base + l15;
        r = r < nrows ? r : nrows - 1;  // clamp; tail discarded at store
        const unsigned short* a0 = A0 + (size_t)r * DIM + lhi * 8;
#pragma unroll
        for (int k = 0; k < 4; ++k) af[0][k] = *(const bf16x8*)(a0 + k * 32);
        if (NSEG == 2) {
            const unsigned short* a1 = A1 + (size_t)r * DIM + lhi * 8;
#pragma unroll
            for (int k = 0; k < 4; ++k) af[1][k] = *(const bf16x8*)(a1 + k * 32);
        }
    }

#pragma unroll
    for (int s = 0; s < NSEG; ++s) {
        const unsigned short* W = s ? W1 : W0;
        const unsigned short* wb = W + (size_t)l15 * DIM + lhi * 8;
#pragma unroll
        for (int k = 0; k < 4; ++k) {
            bf16x8 bf[8];
#pragma unroll
            for (int ct = 0; ct < 8; ++ct)
                bf[ct] = *(const bf16x8*)(wb + (size_t)ct * 16 * DIM + k * 32);
#pragma unroll
            for (int ct = 0; ct < 8; ++ct)
                acc[ct] = __builtin_amdgcn_mfma_f32_16x16x32_bf16(af[s][k], bf[ct],
                                                                  acc[ct], 0, 0, 0);
        }
    }

    // ---- epilogue: C/D map col=lane&15, row=(lane>>4)*4+reg ----
#pragma unroll
    for (int ct = 0; ct < 8; ++ct) {
        int c = ct * 16 + l15;
        float scl, sh;
        if (gamma) {
            float s = gamma[c] * rsqrtf(var[c] + BN_EPS);
            scl = s;
            sh = (bias[c] - mean[c]) * s + beta[c];
        } else {
            scl = 1.f;
            sh = bias[c];
        }
        int rbase = row_base + lhi * 4;
#pragma unroll
        for (int j = 0; j < 4; ++j) {
            int r = rbase + j;
            if (r >= nrows) continue;
            float h = acc[ct][j] * scl + sh;
            h = fmaxf(h, 0.f);
            size_t off = (size_t)r * DIM + c;
            if (residb) h += b2f(residb[off]);
            if (out32) out32[off] = h;
            if (outb) outb[off] = f2b(h);
        }
    }
}

extern "C" void kernel_launch(void* const* d_in, const int* in_sizes, int n_in,
                              void* d_out, int out_size, void* d_ws, size_t ws_size,
                              hipStream_t stream) {
    const float* x_in = (const float*)d_in[0];
    const int* ei     = (const int*)d_in[1];
    const float* Wp   = (const float*)d_in[2];
    const float* bp   = (const float*)d_in[3];
    const float* Wl   = (const float*)d_in[4];
    const float* bl   = (const float*)d_in[5];
    const float* Wr   = (const float*)d_in[6];
    const float* g    = (const float*)d_in[7];
    const float* be   = (const float*)d_in[8];
    const float* mu   = (const float*)d_in[9];
    const float* va   = (const float*)d_in[10];

    const int N = in_sizes[0] / DIM;
    const int E = in_sizes[1] / 2;
    const int* src = ei;
    const int* dst = ei + E;
    const int nchunk = (N + CHUNK - 1) / CHUNK;

    // ---- workspace carve (256B aligned) ----
    char* p = (char*)d_ws;
    auto alloc = [&](size_t bytes) {
        char* r = p;
        p += (bytes + 255) & ~(size_t)255;
        return r;
    };
    float* inv_deg = (float*)alloc((size_t)N * 4);
    int* deg       = (int*)alloc((size_t)N * 4);  // reused as cursor
    int* rowptr    = (int*)alloc((size_t)(N + 1) * 4);
    int* csum      = (int*)alloc((size_t)nchunk * 4);
    int* col       = (int*)alloc((size_t)E * 4);
    unsigned short* xb   = (unsigned short*)alloc((size_t)N * DIM * 2);
    unsigned short* aggb = (unsigned short*)alloc((size_t)N * DIM * 2);
    unsigned short* WT   = (unsigned short*)alloc((size_t)9 * DIM * DIM * 2);

    // ---- CSR build ----
    hipMemsetAsync(deg, 0, (size_t)N * 4, stream);
    k_deg<<<1024, 256, 0, stream>>>(dst, deg, E);
    k_chunksum<<<(nchunk + 255) / 256, 256, 0, stream>>>(deg, csum, nchunk, N);
    k_scanchunks<<<1, 1024, 0, stream>>>(csum, nchunk);
    k_scatter<<<(nchunk + 255) / 256, 256, 0, stream>>>(deg, csum, rowptr, inv_deg,
                                                        nchunk, N, E);
    hipMemsetAsync(deg, 0, (size_t)N * 4, stream);
    k_fill<<<1024, 256, 0, stream>>>(src, dst, rowptr, deg, col, E);

    // ---- weights: transpose + bf16 ----
    k_wtr<<<(9 * DIM * DIM + 255) / 256, 256, 0, stream>>>(Wp, Wl, Wr, WT);
    const unsigned short* WpT = WT;
    // ---- x_in -> bf16 ----
    k_cvt<<<(N * DIM / 4 + 255) / 256, 256, 0, stream>>>(x_in, xb, N * DIM / 4);

    const int gblocks = (N + 63) / 64;

    // ---- x = relu(x_in @ Wp + bp): bf16 out only ----
    k_gemm_mfma<1><<<gblocks, 256, 0, stream>>>(xb, WpT, nullptr, nullptr, bp,
                                                nullptr, nullptr, nullptr, nullptr,
                                                nullptr, nullptr, xb, N);

    float* out = (float*)d_out;
    for (int i = 0; i < 4; ++i) {
        k_agg<<<(N + 3) / 4, 256, 0, stream>>>((const uint4*)xb, rowptr, col,
                                               inv_deg, (uint4*)aggb, N);
        const unsigned short* WlT = WT + (size_t)(1 + i) * DIM * DIM;
        const unsigned short* WrT = WT + (size_t)(5 + i) * DIM * DIM;
        // layers 0..2: xb = bf16(xb + relu(bn(h)));  layer 3: out = relu(bn(h)) fp32
        k_gemm_mfma<2><<<gblocks, 256, 0, stream>>>(
            aggb, WlT, xb, WrT, bl + i * DIM,
            g + i * DIM, be + i * DIM, mu + i * DIM, va + i * DIM,
            (i < 3) ? xb : nullptr,
            (i < 3) ? nullptr : out, (i < 3) ? xb : nullptr, N);
    }
}

// Round 5
// 378.563 us; speedup vs baseline: 2.2200x; 1.2104x over previous
//
#include <hip/hip_runtime.h>

#define DIM 128
#define BN_EPS 1e-5f
#define BCAP 8192        // per-bucket capacity (mean ~4082 for E=800k, NB=196)
#define EPB 4096         // edges per k_bin block
#define EPT 16           // edges per thread in k_bin

typedef __bf16 bf16x8 __attribute__((ext_vector_type(8)));
typedef float f32x4 __attribute__((ext_vector_type(4)));

__device__ __forceinline__ float bf_e0(unsigned int u) {
    return __builtin_bit_cast(float, u << 16);
}
__device__ __forceinline__ float bf_e1(unsigned int u) {
    return __builtin_bit_cast(float, u & 0xffff0000u);
}
__device__ __forceinline__ float b2f(unsigned short s) {
    return __builtin_bit_cast(float, (unsigned int)s << 16);
}
__device__ __forceinline__ unsigned short f2b(float f) {
    __bf16 b = (__bf16)f;  // RTN hardware convert
    return __builtin_bit_cast(unsigned short, b);
}
__device__ __forceinline__ unsigned int pack2(float lo, float hi) {
    return (unsigned int)f2b(lo) | ((unsigned int)f2b(hi) << 16);
}

// ---------------- pass 1: bin edges by dst>>8 into fixed-cap bucket regions ----
// entry: (dst&255)<<17 | src   (requires N <= 2^17)
__global__ __launch_bounds__(256) void k_bin(const int* __restrict__ src,
                                             const int* __restrict__ dst,
                                             int* __restrict__ cursor,
                                             unsigned int* __restrict__ binned,
                                             int E, int NB) {
    __shared__ int hist[256];
    __shared__ int base[256];
    __shared__ int c2[256];
    const int tid = threadIdx.x;
    const int e0 = blockIdx.x * EPB;

    unsigned int u[EPT];
    int b[EPT];
    hist[tid] = 0;
    c2[tid] = 0;
    __syncthreads();
#pragma unroll
    for (int i = 0; i < EPT; ++i) {
        int e = e0 + i * 256 + tid;
        if (e < E) {
            int d = dst[e];
            b[i] = d >> 8;
            u[i] = ((unsigned int)(d & 255) << 17) | (unsigned int)src[e];
            atomicAdd(&hist[b[i]], 1);
        } else {
            b[i] = -1;
        }
    }
    __syncthreads();
    if (tid < NB && hist[tid] > 0) base[tid] = atomicAdd(&cursor[tid], hist[tid]);
    __syncthreads();
#pragma unroll
    for (int i = 0; i < EPT; ++i) {
        if (b[i] < 0) continue;
        int p = base[b[i]] + atomicAdd(&c2[b[i]], 1);
        if (p < BCAP) binned[(size_t)b[i] * BCAP + p] = u[i];
    }
}

// ---------------- pass 2: exclusive scan of bucket counts ----------------
__global__ __launch_bounds__(256) void k_bscan(const int* __restrict__ cursor,
                                               int* __restrict__ bbase,
                                               int* __restrict__ rowptr, int NB,
                                               int N, int E) {
    __shared__ int sh[256];
    int t = threadIdx.x;
    int v = (t < NB) ? min(cursor[t], BCAP) : 0;
    sh[t] = v;
    __syncthreads();
    for (int off = 1; off < 256; off <<= 1) {
        int a = (t >= off) ? sh[t - off] : 0;
        __syncthreads();
        sh[t] += a;
        __syncthreads();
    }
    if (t < NB) bbase[t] = sh[t] - v;
    if (t == 0) rowptr[N] = E;
}

// ---------------- pass 3: per-bucket CSR (deg, rowptr, inv_deg, col) --------
// One block per bucket; col writes span one contiguous ~16KB range -> XCD-local.
__global__ __launch_bounds__(256) void k_csr(const int* __restrict__ cursor,
                                             const int* __restrict__ bbase,
                                             const unsigned int* __restrict__ binned,
                                             int* __restrict__ rowptr,
                                             float* __restrict__ inv_deg,
                                             int* __restrict__ col, int N) {
    __shared__ unsigned int stage[BCAP];   // 32 KB
    __shared__ int deg[256];
    __shared__ int start[256];
    const int b = blockIdx.x;
    const int t = threadIdx.x;
    const int node0 = b << 8;
    const int cnt = min(cursor[b], BCAP);
    const int gbase = bbase[b];

    deg[t] = 0;
    __syncthreads();
    for (int e = t; e < cnt; e += 256) {
        unsigned int u = binned[(size_t)b * BCAP + e];
        stage[e] = u;
        atomicAdd(&deg[u >> 17], 1);
    }
    __syncthreads();
    int d = deg[t];
    start[t] = d;
    __syncthreads();
    for (int off = 1; off < 256; off <<= 1) {
        int a = (t >= off) ? start[t - off] : 0;
        __syncthreads();
        start[t] += a;
        __syncthreads();
    }
    int excl = start[t] - d;
    int node = node0 + t;
    if (node < N) {
        rowptr[node] = gbase + excl;
        inv_deg[node] = 1.0f / (float)(d > 1 ? d : 1);
    }
    __syncthreads();
    deg[t] = excl;  // reuse as running cursor
    __syncthreads();
    for (int e = t; e < cnt; e += 256) {
        unsigned int u = stage[e];
        int dl = u >> 17;
        int p = atomicAdd(&deg[dl], 1);
        col[gbase + p] = (int)(u & 0x1ffffu);
    }
}

// ---------------- weight transpose + bf16: WT[m][n][k] = bf16(W_m[k][n]) ----
__global__ void k_wtr(const float* __restrict__ Wp, const float* __restrict__ Wl,
                      const float* __restrict__ Wr, unsigned short* __restrict__ WT) {
    int e = blockIdx.x * blockDim.x + threadIdx.x;
    if (e >= 9 * DIM * DIM) return;
    int m = e / (DIM * DIM);
    int r = e % (DIM * DIM);
    int n = r / DIM;
    int k = r % DIM;
    const float* W = (m == 0) ? Wp : (m < 5) ? (Wl + (size_t)(m - 1) * DIM * DIM)
                                             : (Wr + (size_t)(m - 5) * DIM * DIM);
    WT[e] = f2b(W[(size_t)k * DIM + n]);
}

// ---------------- mean aggregation: wave = 1 node, 4 edge-groups x 16 lanes ----
__global__ void k_agg(const uint4* __restrict__ xb4, const int* __restrict__ rowptr,
                      const int* __restrict__ col, const float* __restrict__ inv_deg,
                      uint4* __restrict__ aggb4, int n) {
    int node = (blockIdx.x * blockDim.x + threadIdx.x) >> 6;
    int lane = threadIdx.x & 63;
    if (node >= n) return;
    const int e4 = lane >> 4, c16 = lane & 15;
    const int lo = rowptr[node], hi = rowptr[node + 1];

    float a0 = 0.f, a1 = 0.f, a2 = 0.f, a3 = 0.f,
          a4 = 0.f, a5 = 0.f, a6 = 0.f, a7 = 0.f;

    int idx = lo + e4;
    int s_pre = (idx < hi) ? col[idx] : -1;  // prefetched col for this iter
    for (int j = lo; j < hi; j += 4) {
        int s = s_pre;
        int nidx = j + 4 + e4;
        s_pre = (nidx < hi) ? col[nidx] : -1;  // overlap next col load with gather
        if (s >= 0) {
            uint4 v = xb4[(size_t)s * 16 + c16];
            a0 += bf_e0(v.x); a1 += bf_e1(v.x);
            a2 += bf_e0(v.y); a3 += bf_e1(v.y);
            a4 += bf_e0(v.z); a5 += bf_e1(v.z);
            a6 += bf_e0(v.w); a7 += bf_e1(v.w);
        }
    }
#define RED_(a) a += __shfl_xor(a, 16); a += __shfl_xor(a, 32);
    RED_(a0) RED_(a1) RED_(a2) RED_(a3) RED_(a4) RED_(a5) RED_(a6) RED_(a7)
#undef RED_
    float sc = inv_deg[node];
    uint4 o;
    o.x = pack2(a0 * sc, a1 * sc);
    o.y = pack2(a2 * sc, a3 * sc);
    o.z = pack2(a4 * sc, a5 * sc);
    o.w = pack2(a6 * sc, a7 * sc);
    if (lane < 16) aggb4[(size_t)node * 16 + c16] = o;
}

// ---------------- MFMA dual-GEMM + bias + BN + ReLU + bf16 residual ----------
// wave = 16 rows x 128 cols; block = 4 waves = 64 rows; grid = N/64.
template <int NSEG, bool A0F32>
__global__ __launch_bounds__(256) void k_gemm_mfma(
    const void* __restrict__ A0v, const unsigned short* __restrict__ W0,
    const unsigned short* __restrict__ A1, const unsigned short* __restrict__ W1,
    const float* __restrict__ bias,
    const float* __restrict__ gamma, const float* __restrict__ beta,
    const float* __restrict__ mean, const float* __restrict__ var,
    const unsigned short* __restrict__ residb,
    float* __restrict__ out32, unsigned short* __restrict__ outb, int nrows) {
    const int lane = threadIdx.x & 63;
    const int wave = threadIdx.x >> 6;
    const int l15 = lane & 15;
    const int lhi = lane >> 4;
    const int row_base = blockIdx.x * 64 + wave * 16;

    f32x4 acc[8];
#pragma unroll
    for (int ct = 0; ct < 8; ++ct) acc[ct] = (f32x4){0.f, 0.f, 0.f, 0.f};

    // ---- A fragments: row = row_base + l15, k = k*32 + lhi*8 .. +7
    bf16x8 af[NSEG][4];
    {
        int r = row_base + l15;
        r = r < nrows ? r : nrows - 1;  // clamp; tail discarded at store
        if (A0F32) {
            const float* a0 = (const float*)A0v + (size_t)r * DIM + lhi * 8;
#pragma unroll
            for (int k = 0; k < 4; ++k) {
                float4 v0 = *(const float4*)(a0 + k * 32);
                float4 v1 = *(const float4*)(a0 + k * 32 + 4);
                bf16x8 f;
                f[0] = (__bf16)v0.x; f[1] = (__bf16)v0.y;
                f[2] = (__bf16)v0.z; f[3] = (__bf16)v0.w;
                f[4] = (__bf16)v1.x; f[5] = (__bf16)v1.y;
                f[6] = (__bf16)v1.z; f[7] = (__bf16)v1.w;
                af[0][k] = f;
            }
        } else {
            const unsigned short* a0 = (const unsigned short*)A0v + (size_t)r * DIM + lhi * 8;
#pragma unroll
            for (int k = 0; k < 4; ++k) af[0][k] = *(const bf16x8*)(a0 + k * 32);
        }
        if (NSEG == 2) {
            const unsigned short* a1 = A1 + (size_t)r * DIM + lhi * 8;
#pragma unroll
            for (int k = 0; k < 4; ++k) af[1][k] = *(const bf16x8*)(a1 + k * 32);
        }
    }

#pragma unroll
    for (int s = 0; s < NSEG; ++s) {
        const unsigned short* W = s ? W1 : W0;
        const unsigned short* wb = W + (size_t)l15 * DIM + lhi * 8;
#pragma unroll
        for (int k = 0; k < 4; ++k) {
            bf16x8 bf[8];
#pragma unroll
            for (int ct = 0; ct < 8; ++ct)
                bf[ct] = *(const bf16x8*)(wb + (size_t)ct * 16 * DIM + k * 32);
#pragma unroll
            for (int ct = 0; ct < 8; ++ct)
                acc[ct] = __builtin_amdgcn_mfma_f32_16x16x32_bf16(af[s][k], bf[ct],
                                                                  acc[ct], 0, 0, 0);
        }
    }

    // ---- epilogue: C/D map col=lane&15, row=(lane>>4)*4+reg ----
#pragma unroll
    for (int ct = 0; ct < 8; ++ct) {
        int c = ct * 16 + l15;
        float scl, sh;
        if (gamma) {
            float s = gamma[c] * rsqrtf(var[c] + BN_EPS);
            scl = s;
            sh = (bias[c] - mean[c]) * s + beta[c];
        } else {
            scl = 1.f;
            sh = bias[c];
        }
        int rbase = row_base + lhi * 4;
#pragma unroll
        for (int j = 0; j < 4; ++j) {
            int r = rbase + j;
            if (r >= nrows) continue;
            float h = acc[ct][j] * scl + sh;
            h = fmaxf(h, 0.f);
            size_t off = (size_t)r * DIM + c;
            if (residb) h += b2f(residb[off]);
            if (out32) out32[off] = h;
            if (outb) outb[off] = f2b(h);
        }
    }
}

extern "C" void kernel_launch(void* const* d_in, const int* in_sizes, int n_in,
                              void* d_out, int out_size, void* d_ws, size_t ws_size,
                              hipStream_t stream) {
    const float* x_in = (const float*)d_in[0];
    const int* ei     = (const int*)d_in[1];
    const float* Wp   = (const float*)d_in[2];
    const float* bp   = (const float*)d_in[3];
    const float* Wl   = (const float*)d_in[4];
    const float* bl   = (const float*)d_in[5];
    const float* Wr   = (const float*)d_in[6];
    const float* g    = (const float*)d_in[7];
    const float* be   = (const float*)d_in[8];
    const float* mu   = (const float*)d_in[9];
    const float* va   = (const float*)d_in[10];

    const int N = in_sizes[0] / DIM;
    const int E = in_sizes[1] / 2;
    const int* src = ei;
    const int* dst = ei + E;
    const int NB = (N + 255) >> 8;  // buckets of 256 nodes

    // ---- workspace carve (256B aligned) ----
    char* p = (char*)d_ws;
    auto alloc = [&](size_t bytes) {
        char* r = p;
        p += (bytes + 255) & ~(size_t)255;
        return r;
    };
    float* inv_deg = (float*)alloc((size_t)N * 4);
    int* rowptr    = (int*)alloc((size_t)(N + 1) * 4);
    int* cursor    = (int*)alloc((size_t)NB * 4);
    int* bbase     = (int*)alloc((size_t)NB * 4);
    int* col       = (int*)alloc((size_t)E * 4);
    unsigned int* binned = (unsigned int*)alloc((size_t)NB * BCAP * 4);
    unsigned short* xb   = (unsigned short*)alloc((size_t)N * DIM * 2);
    unsigned short* aggb = (unsigned short*)alloc((size_t)N * DIM * 2);
    unsigned short* WT   = (unsigned short*)alloc((size_t)9 * DIM * DIM * 2);

    // ---- CSR build: bin -> scan -> per-bucket fill (XCD-local col writes) ----
    hipMemsetAsync(cursor, 0, (size_t)NB * 4, stream);
    k_bin<<<(E + EPB - 1) / EPB, 256, 0, stream>>>(src, dst, cursor, binned, E, NB);
    k_bscan<<<1, 256, 0, stream>>>(cursor, bbase, rowptr, NB, N, E);
    k_csr<<<NB, 256, 0, stream>>>(cursor, bbase, binned, rowptr, inv_deg, col, N);

    // ---- weights: transpose + bf16 ----
    k_wtr<<<(9 * DIM * DIM + 255) / 256, 256, 0, stream>>>(Wp, Wl, Wr, WT);
    const unsigned short* WpT = WT;

    const int gblocks = (N + 63) / 64;

    // ---- x = relu(x_in @ Wp + bp): fp32 A path, bf16 out ----
    k_gemm_mfma<1, true><<<gblocks, 256, 0, stream>>>(
        x_in, WpT, nullptr, nullptr, bp,
        nullptr, nullptr, nullptr, nullptr, nullptr, nullptr, xb, N);

    float* out = (float*)d_out;
    for (int i = 0; i < 4; ++i) {
        k_agg<<<(N + 3) / 4, 256, 0, stream>>>((const uint4*)xb, rowptr, col,
                                               inv_deg, (uint4*)aggb, N);
        const unsigned short* WlT = WT + (size_t)(1 + i) * DIM * DIM;
        const unsigned short* WrT = WT + (size_t)(5 + i) * DIM * DIM;
        // layers 0..2: xb = bf16(xb + relu(bn(h)));  layer 3: out = relu(bn(h)) fp32
        k_gemm_mfma<2, false><<<gblocks, 256, 0, stream>>>(
            aggb, WlT, xb, WrT, bl + i * DIM,
            g + i * DIM, be + i * DIM, mu + i * DIM, va + i * DIM,
            (i < 3) ? xb : nullptr,
            (i < 3) ? nullptr : out, (i < 3) ? xb : nullptr, N);
    }
}

// Round 6
// 249.204 us; speedup vs baseline: 3.3724x; 1.5191x over previous
//
#include <hip/hip_runtime.h>

#define DIM 128
#define BN_EPS 1e-5f
#define BCAP 8192        // per-bucket capacity (mean ~4082 for E=800k, NB=196)
#define EPB 4096         // edges per k_bin block
#define EPT 16           // edges per thread in k_bin

typedef __bf16 bf16x8 __attribute__((ext_vector_type(8)));
typedef float f32x4 __attribute__((ext_vector_type(4)));

__device__ __forceinline__ float bf_e0(unsigned int u) {
    return __builtin_bit_cast(float, u << 16);
}
__device__ __forceinline__ float bf_e1(unsigned int u) {
    return __builtin_bit_cast(float, u & 0xffff0000u);
}
__device__ __forceinline__ unsigned short f2b(float f) {
    __bf16 b = (__bf16)f;  // RTN hardware convert
    return __builtin_bit_cast(unsigned short, b);
}
__device__ __forceinline__ unsigned int pack2(float lo, float hi) {
    return (unsigned int)f2b(lo) | ((unsigned int)f2b(hi) << 16);
}

// ---------------- pass 1: bin edges by dst>>8 into fixed-cap bucket regions ----
// entry: (dst&255)<<17 | src   (requires N <= 2^17)
__global__ __launch_bounds__(256) void k_bin(const int* __restrict__ src,
                                             const int* __restrict__ dst,
                                             int* __restrict__ cursor,
                                             unsigned int* __restrict__ binned,
                                             int E, int NB) {
    __shared__ int hist[256];
    __shared__ int base[256];
    __shared__ int c2[256];
    const int tid = threadIdx.x;
    const int e0 = blockIdx.x * EPB;

    unsigned int u[EPT];
    int b[EPT];
    hist[tid] = 0;
    c2[tid] = 0;
    __syncthreads();
#pragma unroll
    for (int i = 0; i < EPT; ++i) {
        int e = e0 + i * 256 + tid;
        if (e < E) {
            int d = dst[e];
            b[i] = d >> 8;
            u[i] = ((unsigned int)(d & 255) << 17) | (unsigned int)src[e];
            atomicAdd(&hist[b[i]], 1);
        } else {
            b[i] = -1;
        }
    }
    __syncthreads();
    if (tid < NB && hist[tid] > 0) base[tid] = atomicAdd(&cursor[tid], hist[tid]);
    __syncthreads();
#pragma unroll
    for (int i = 0; i < EPT; ++i) {
        if (b[i] < 0) continue;
        int p = base[b[i]] + atomicAdd(&c2[b[i]], 1);
        if (p < BCAP) binned[(size_t)b[i] * BCAP + p] = u[i];
    }
}

// ---------------- pass 2: exclusive scan of bucket counts ----------------
__global__ __launch_bounds__(256) void k_bscan(const int* __restrict__ cursor,
                                               int* __restrict__ bbase,
                                               int* __restrict__ rowptr, int NB,
                                               int N, int E) {
    __shared__ int sh[256];
    int t = threadIdx.x;
    int v = (t < NB) ? min(cursor[t], BCAP) : 0;
    sh[t] = v;
    __syncthreads();
    for (int off = 1; off < 256; off <<= 1) {
        int a = (t >= off) ? sh[t - off] : 0;
        __syncthreads();
        sh[t] += a;
        __syncthreads();
    }
    if (t < NB) bbase[t] = sh[t] - v;
    if (t == 0) rowptr[N] = E;
}

// ---------------- pass 3: per-bucket CSR (deg, rowptr, inv_deg, col) --------
__global__ __launch_bounds__(256) void k_csr(const int* __restrict__ cursor,
                                             const int* __restrict__ bbase,
                                             const unsigned int* __restrict__ binned,
                                             int* __restrict__ rowptr,
                                             float* __restrict__ inv_deg,
                                             int* __restrict__ col, int N) {
    __shared__ unsigned int stage[BCAP];   // 32 KB
    __shared__ int deg[256];
    __shared__ int start[256];
    const int b = blockIdx.x;
    const int t = threadIdx.x;
    const int node0 = b << 8;
    const int cnt = min(cursor[b], BCAP);
    const int gbase = bbase[b];

    deg[t] = 0;
    __syncthreads();
    for (int e = t; e < cnt; e += 256) {
        unsigned int u = binned[(size_t)b * BCAP + e];
        stage[e] = u;
        atomicAdd(&deg[u >> 17], 1);
    }
    __syncthreads();
    int d = deg[t];
    start[t] = d;
    __syncthreads();
    for (int off = 1; off < 256; off <<= 1) {
        int a = (t >= off) ? start[t - off] : 0;
        __syncthreads();
        start[t] += a;
        __syncthreads();
    }
    int excl = start[t] - d;
    int node = node0 + t;
    if (node < N) {
        rowptr[node] = gbase + excl;
        inv_deg[node] = 1.0f / (float)(d > 1 ? d : 1);
    }
    __syncthreads();
    deg[t] = excl;  // reuse as running cursor
    __syncthreads();
    for (int e = t; e < cnt; e += 256) {
        unsigned int u = stage[e];
        int dl = u >> 17;
        int p = atomicAdd(&deg[dl], 1);
        col[gbase + p] = (int)(u & 0x1ffffu);
    }
}

// ---------------- weights -> bf16, FRAGMENT-MAJOR layout ----------------
// WTf[m] is 16384 shorts: frag (ct,k,lane) at ((ct*4+k)*64+lane)*8, holding
// W^T[ct*16+(lane&15)][k*32+(lane>>4)*8+e] for e=0..7 (A-operand layout).
__global__ void k_wtr(const float* __restrict__ Wp, const float* __restrict__ Wl,
                      const float* __restrict__ Wr, unsigned short* __restrict__ WTf) {
    int gid = blockIdx.x * blockDim.x + threadIdx.x;
    if (gid >= 9 * 2048) return;
    int m = gid >> 11;
    int r = gid & 2047;
    int lane = r & 63;
    int k = (r >> 6) & 3;
    int ct = r >> 8;
    int feat = ct * 16 + (lane & 15);
    int kb = k * 32 + (lane >> 4) * 8;
    const float* W = (m == 0) ? Wp : (m < 5) ? (Wl + (size_t)(m - 1) * DIM * DIM)
                                             : (Wr + (size_t)(m - 5) * DIM * DIM);
    unsigned short o[8];
#pragma unroll
    for (int e = 0; e < 8; ++e) o[e] = f2b(W[(size_t)(kb + e) * DIM + feat]);
    *(uint4*)(WTf + (size_t)gid * 8) = *(const uint4*)o;
}

// ---------------- mean aggregation: wave = 1 node, 4 edge-groups x 16 lanes ----
__global__ void k_agg(const uint4* __restrict__ xb4, const int* __restrict__ rowptr,
                      const int* __restrict__ col, const float* __restrict__ inv_deg,
                      uint4* __restrict__ aggb4, int n) {
    int node = (blockIdx.x * blockDim.x + threadIdx.x) >> 6;
    int lane = threadIdx.x & 63;
    if (node >= n) return;
    const int e4 = lane >> 4, c16 = lane & 15;
    const int lo = rowptr[node], hi = rowptr[node + 1];

    float a0 = 0.f, a1 = 0.f, a2 = 0.f, a3 = 0.f,
          a4 = 0.f, a5 = 0.f, a6 = 0.f, a7 = 0.f;

    int idx = lo + e4;
    int s_pre = (idx < hi) ? col[idx] : -1;
    for (int j = lo; j < hi; j += 4) {
        int s = s_pre;
        int nidx = j + 4 + e4;
        s_pre = (nidx < hi) ? col[nidx] : -1;
        if (s >= 0) {
            uint4 v = xb4[(size_t)s * 16 + c16];
            a0 += bf_e0(v.x); a1 += bf_e1(v.x);
            a2 += bf_e0(v.y); a3 += bf_e1(v.y);
            a4 += bf_e0(v.z); a5 += bf_e1(v.z);
            a6 += bf_e0(v.w); a7 += bf_e1(v.w);
        }
    }
#define RED_(a) a += __shfl_xor(a, 16); a += __shfl_xor(a, 32);
    RED_(a0) RED_(a1) RED_(a2) RED_(a3) RED_(a4) RED_(a5) RED_(a6) RED_(a7)
#undef RED_
    float sc = inv_deg[node];
    uint4 o;
    o.x = pack2(a0 * sc, a1 * sc);
    o.y = pack2(a2 * sc, a3 * sc);
    o.z = pack2(a4 * sc, a5 * sc);
    o.w = pack2(a6 * sc, a7 * sc);
    if (lane < 16) aggb4[(size_t)node * 16 + c16] = o;
}

// ---------------- MFMA dual-GEMM, LDS-staged W, operand-swapped ----------
// block = 256 thr = 4 waves; wave = 16 nodes x 128 feats; grid = N/64.
// D[feat][node] = mfma(Wfrag, xfrag): thread holds feats ct*16+lhi*4..+3 of
// node (row_base + l15)  ->  packed 8B epilogue stores.
template <int NSEG, bool A0F32>
__global__ __launch_bounds__(256) void k_gemm(
    const void* __restrict__ A0v, const unsigned short* __restrict__ A1,
    const unsigned short* __restrict__ Wf0, const unsigned short* __restrict__ Wf1,
    const float* __restrict__ bias,
    const float* __restrict__ gamma, const float* __restrict__ beta,
    const float* __restrict__ mean, const float* __restrict__ var,
    const unsigned short* __restrict__ residb,
    float* __restrict__ out32, unsigned short* __restrict__ outb, int nrows) {
    __shared__ unsigned short wlds[16384];  // 32 KB: one segment's frags
    __shared__ float colp[2 * DIM];         // per-col (scale, shift)

    const int tid = threadIdx.x;
    const int lane = tid & 63;
    const int wave = tid >> 6;
    const int l15 = lane & 15;
    const int lhi = lane >> 4;
    const int node = blockIdx.x * 64 + wave * 16 + l15;
    const int arow = node < nrows ? node : nrows - 1;  // clamped read row

    // per-column BN scale/shift -> LDS (once)
    if (tid < DIM) {
        float sc, sh;
        if (gamma) {
            float s = gamma[tid] * rsqrtf(var[tid] + BN_EPS);
            sc = s;
            sh = (bias[tid] - mean[tid]) * s + beta[tid];
        } else {
            sc = 1.f;
            sh = bias[tid];
        }
        colp[tid * 2] = sc;
        colp[tid * 2 + 1] = sh;
    }

    f32x4 acc[8];
#pragma unroll
    for (int ct = 0; ct < 8; ++ct) acc[ct] = (f32x4){0.f, 0.f, 0.f, 0.f};

    // ---- stage seg0 W frags (coalesced uint4, linear) ----
    {
        const uint4* g = (const uint4*)Wf0;
        uint4* l = (uint4*)wlds;
#pragma unroll
        for (int i = 0; i < 8; ++i) l[tid + i * 256] = g[tid + i * 256];
    }
    __syncthreads();

    // ---- seg0: A-frags from global, B(W)-frags from LDS ----
    {
        bf16x8 af[4];
        if (A0F32) {
            const float* a0 = (const float*)A0v + (size_t)arow * DIM + lhi * 8;
#pragma unroll
            for (int k = 0; k < 4; ++k) {
                float4 v0 = *(const float4*)(a0 + k * 32);
                float4 v1 = *(const float4*)(a0 + k * 32 + 4);
                bf16x8 f;
                f[0] = (__bf16)v0.x; f[1] = (__bf16)v0.y;
                f[2] = (__bf16)v0.z; f[3] = (__bf16)v0.w;
                f[4] = (__bf16)v1.x; f[5] = (__bf16)v1.y;
                f[6] = (__bf16)v1.z; f[7] = (__bf16)v1.w;
                af[k] = f;
            }
        } else {
            const unsigned short* a0 = (const unsigned short*)A0v + (size_t)arow * DIM + lhi * 8;
#pragma unroll
            for (int k = 0; k < 4; ++k) af[k] = *(const bf16x8*)(a0 + k * 32);
        }
#pragma unroll
        for (int k = 0; k < 4; ++k) {
            bf16x8 bw[8];
#pragma unroll
            for (int ct = 0; ct < 8; ++ct)
                bw[ct] = *(const bf16x8*)&wlds[((ct * 4 + k) * 64 + lane) * 8];
#pragma unroll
            for (int ct = 0; ct < 8; ++ct)
                acc[ct] = __builtin_amdgcn_mfma_f32_16x16x32_bf16(bw[ct], af[k],
                                                                  acc[ct], 0, 0, 0);
        }
    }

    if (NSEG == 2) {
        __syncthreads();  // all waves done with seg0 frags
        {
            const uint4* g = (const uint4*)Wf1;
            uint4* l = (uint4*)wlds;
#pragma unroll
            for (int i = 0; i < 8; ++i) l[tid + i * 256] = g[tid + i * 256];
        }
        __syncthreads();
        bf16x8 af[4];
        const unsigned short* a1 = A1 + (size_t)arow * DIM + lhi * 8;
#pragma unroll
        for (int k = 0; k < 4; ++k) af[k] = *(const bf16x8*)(a1 + k * 32);
#pragma unroll
        for (int k = 0; k < 4; ++k) {
            bf16x8 bw[8];
#pragma unroll
            for (int ct = 0; ct < 8; ++ct)
                bw[ct] = *(const bf16x8*)&wlds[((ct * 4 + k) * 64 + lane) * 8];
#pragma unroll
            for (int ct = 0; ct < 8; ++ct)
                acc[ct] = __builtin_amdgcn_mfma_f32_16x16x32_bf16(bw[ct], af[k],
                                                                  acc[ct], 0, 0, 0);
        }
    } else {
        __syncthreads();  // colp visibility for epilogue
    }

    // ---- epilogue: thread owns feats ct*16+lhi*4..+3 of node ----
    if (node < nrows) {
#pragma unroll
        for (int ct = 0; ct < 8; ++ct) {
            int c0 = ct * 16 + lhi * 4;
            float h[4];
#pragma unroll
            for (int j = 0; j < 4; ++j) {
                float2 p = *(const float2*)&colp[(c0 + j) * 2];
                h[j] = fmaxf(acc[ct][j] * p.x + p.y, 0.f);
            }
            size_t base = (size_t)node * DIM + c0;
            if (residb) {
                uint2 rv = *(const uint2*)(residb + base);
                h[0] += bf_e0(rv.x); h[1] += bf_e1(rv.x);
                h[2] += bf_e0(rv.y); h[3] += bf_e1(rv.y);
            }
            if (outb) {
                uint2 o;
                o.x = pack2(h[0], h[1]);
                o.y = pack2(h[2], h[3]);
                *(uint2*)(outb + base) = o;
            }
            if (out32)
                *(float4*)(out32 + base) = make_float4(h[0], h[1], h[2], h[3]);
        }
    }
}

extern "C" void kernel_launch(void* const* d_in, const int* in_sizes, int n_in,
                              void* d_out, int out_size, void* d_ws, size_t ws_size,
                              hipStream_t stream) {
    const float* x_in = (const float*)d_in[0];
    const int* ei     = (const int*)d_in[1];
    const float* Wp   = (const float*)d_in[2];
    const float* bp   = (const float*)d_in[3];
    const float* Wl   = (const float*)d_in[4];
    const float* bl   = (const float*)d_in[5];
    const float* Wr   = (const float*)d_in[6];
    const float* g    = (const float*)d_in[7];
    const float* be   = (const float*)d_in[8];
    const float* mu   = (const float*)d_in[9];
    const float* va   = (const float*)d_in[10];

    const int N = in_sizes[0] / DIM;
    const int E = in_sizes[1] / 2;
    const int* src = ei;
    const int* dst = ei + E;
    const int NB = (N + 255) >> 8;  // buckets of 256 nodes

    // ---- workspace carve (256B aligned) ----
    char* p = (char*)d_ws;
    auto alloc = [&](size_t bytes) {
        char* r = p;
        p += (bytes + 255) & ~(size_t)255;
        return r;
    };
    float* inv_deg = (float*)alloc((size_t)N * 4);
    int* rowptr    = (int*)alloc((size_t)(N + 1) * 4);
    int* cursor    = (int*)alloc((size_t)NB * 4);
    int* bbase     = (int*)alloc((size_t)NB * 4);
    int* col       = (int*)alloc((size_t)E * 4);
    unsigned int* binned = (unsigned int*)alloc((size_t)NB * BCAP * 4);
    unsigned short* xb   = (unsigned short*)alloc((size_t)N * DIM * 2);
    unsigned short* aggb = (unsigned short*)alloc((size_t)N * DIM * 2);
    unsigned short* WTf  = (unsigned short*)alloc((size_t)9 * 16384 * 2);

    // ---- CSR build: bin -> scan -> per-bucket fill (XCD-local col writes) ----
    hipMemsetAsync(cursor, 0, (size_t)NB * 4, stream);
    k_bin<<<(E + EPB - 1) / EPB, 256, 0, stream>>>(src, dst, cursor, binned, E, NB);
    k_bscan<<<1, 256, 0, stream>>>(cursor, bbase, rowptr, NB, N, E);
    k_csr<<<NB, 256, 0, stream>>>(cursor, bbase, binned, rowptr, inv_deg, col, N);

    // ---- weights: bf16 fragment-major ----
    k_wtr<<<(9 * 2048 + 255) / 256, 256, 0, stream>>>(Wp, Wl, Wr, WTf);

    const int gblocks = (N + 63) / 64;

    // ---- x = relu(x_in @ Wp + bp): fp32 A path, bf16 out ----
    k_gemm<1, true><<<gblocks, 256, 0, stream>>>(
        x_in, nullptr, WTf, nullptr, bp,
        nullptr, nullptr, nullptr, nullptr, nullptr, nullptr, xb, N);

    float* out = (float*)d_out;
    for (int i = 0; i < 4; ++i) {
        k_agg<<<(N + 3) / 4, 256, 0, stream>>>((const uint4*)xb, rowptr, col,
                                               inv_deg, (uint4*)aggb, N);
        const unsigned short* WlF = WTf + (size_t)(1 + i) * 16384;
        const unsigned short* WrF = WTf + (size_t)(5 + i) * 16384;
        // layers 0..2: xb = bf16(xb + relu(bn(h)));  layer 3: out = relu(bn(h)) fp32
        k_gemm<2, false><<<gblocks, 256, 0, stream>>>(
            aggb, xb, WlF, WrF, bl + i * DIM,
            g + i * DIM, be + i * DIM, mu + i * DIM, va + i * DIM,
            (i < 3) ? xb : nullptr,
            (i < 3) ? nullptr : out, (i < 3) ? xb : nullptr, N);
    }
}